// Round 15
// baseline (1555.051 us; speedup 1.0000x reference)
//
#include <hip/hip_runtime.h>

typedef unsigned short u16;
typedef unsigned int u32;
typedef __attribute__((ext_vector_type(8))) short bf8;   // 8 x bf16 MFMA operand
typedef __attribute__((ext_vector_type(4))) float f4;    // MFMA accumulator

#define DEVI static __device__ __forceinline__

constexpr int Bb = 128, Tt = 512, Dd = 128, Hh = 256, G4 = 1024;

DEVI u16 f2bf(float f) {
  union { float f; u32 u; } v; v.f = f;
  u32 r = v.u + 0x7FFFu + ((v.u >> 16) & 1u);  // RNE
  return (u16)(r >> 16);
}
DEVI float bf2f(u16 b) { union { u32 u; float f; } v; v.u = ((u32)b) << 16; return v.f; }
DEVI float frcp(float x) { return __builtin_amdgcn_rcpf(x); }
DEVI float sigm(float x) { return frcp(1.f + __expf(-x)); }
DEVI float tanh_f(float x) { return 1.f - 2.f * frcp(1.f + __expf(2.f * x)); }
DEVI f4 mfma16(bf8 a, bf8 b, f4 c) {
  return __builtin_amdgcn_mfma_f32_16x16x32_bf16(a, b, c, 0, 0, 0);
}

// ---- device-coherent (MALL-direct, L1/L2-bypass) ops — r8/r10-proven exchange path ----
DEVI u32 ld_u32_coh(const u32* p) {
  u32 r;
  asm volatile("global_load_dword %0, %1, off sc0 sc1\ns_waitcnt vmcnt(0)"
               : "=&v"(r) : "v"(p) : "memory");
  return r;
}
DEVI bf8 ld16_coh(const u16* p) {   // no embedded wait: counted externally
  bf8 r;
  asm volatile("global_load_dwordx4 %0, %1, off sc0 sc1" : "=&v"(r) : "v"(p) : "memory");
  return r;
}
DEVI void st16_coh(u16* p, bf8 v) {
  asm volatile("global_store_dwordx4 %0, %1, off sc0 sc1" :: "v"(p), "v"(v) : "memory");
}
DEVI void st_u32_coh(u32* p, u32 v) {
  asm volatile("global_store_dword %0, %1, off sc0 sc1" :: "v"(p), "v"(v) : "memory");
}
DEVI f4 ld16f(const float* p) {   // plain cached load, asm so compiler adds no waits
  f4 r;
  asm volatile("global_load_dwordx4 %0, %1, off" : "=&v"(r) : "v"(p) : "memory");
  return r;
}

// ---------- prep kernels ----------

__global__ void k_prep_x(const float* __restrict__ X, u16* __restrict__ Xhi, u16* __restrict__ Xlo) {
  size_t idx = (size_t)blockIdx.x * 256 + threadIdx.x;      // (b*T+t)*D + d
  int d = (int)(idx % Dd);
  size_t bt = idx / Dd;
  int b = (int)(bt / Tt), t = (int)(bt % Tt);
  float x = X[idx];
  u16 hi = f2bf(x);
  u16 lo = f2bf(x - bf2f(hi));
  size_t o = ((size_t)t * Bb + b) * Dd + d;
  Xhi[o] = hi; Xlo[o] = lo;
}

__global__ void k_split(const float* __restrict__ W, u16* __restrict__ hi_, u16* __restrict__ lo_) {
  size_t idx = (size_t)blockIdx.x * 256 + threadIdx.x;
  float v = W[idx];
  u16 hi = f2bf(v);
  hi_[idx] = hi;
  lo_[idx] = f2bf(v - bf2f(hi));
}

// Whh[4H,H] -> fragment-linear bf16 W2: offset jtg*4096 + kt*512 + lane*8 + i
__global__ void k_prep_whh(const float* __restrict__ Whh, u16* __restrict__ W2) {
  int idx = blockIdx.x * 256 + threadIdx.x;           // 262144
  int i = idx & 7, lane = (idx >> 3) & 63, kt = (idx >> 9) & 7, jtg = idx >> 12;
  int jp = (jtg << 4) + (lane & 15);
  int k  = ((lane >> 4) << 3) + i + (kt << 5);
  W2[idx] = f2bf(Whh[(size_t)jp * Hh + k]);
}

__global__ void k_bias(const float* __restrict__ a, const float* __restrict__ b, float* __restrict__ o) {
  int i = blockIdx.x * 256 + threadIdx.x;
  if (i < G4) o[i] = a[i] + b[i];
}

// tags[2][Tt+1][8][8]: row 0 = 1 (pre-published), rest 0.
__global__ void k_init(u32* __restrict__ tags) {
  int i = blockIdx.x * 256 + threadIdx.x;
  if (i < 2 * (Tt + 1) * 64) {
    int row = (i >> 6) % (Tt + 1);
    tags[i] = (row == 0) ? 1u : 0u;
  }
}

__global__ void k_zrow(u16* __restrict__ a, u16* __restrict__ b) {
  int i = blockIdx.x * 256 + threadIdx.x;
  if (i < Bb * Hh) { a[i] = 0; b[i] = 0; }
}

// ---------- GEMM body (256 thr): gates = A[M,K] @ W[1024,K]^T + bias -> XGF layout ----------
template <int K, bool ALO>
DEVI void gemm_body(char* smem, const u16* __restrict__ Ahi, const u16* __restrict__ Alo,
                    const u16* __restrict__ Whi, const u16* __restrict__ Wlo,
                    const float* __restrict__ bias, float* __restrict__ Cout,
                    int bx, int by) {
  u16* AsH = (u16*)smem;             // [128][32]
  u16* AsL = (u16*)(smem + 8192);
  const int tid = threadIdx.x, l = tid & 63;
  const int w = tid >> 6, wm = w >> 1, wn = w & 1;
  const int lrow = l & 15, lk = (l >> 4) << 3;
  const size_t m0 = (size_t)bx * 128;
  const int n0 = by * 128;

  f4 acc[4][4];
  size_t colK[4];
#pragma unroll
  for (int ni = 0; ni < 4; ++ni) {
    int col = n0 + wn * 64 + ni * 16 + lrow;
    float bv = bias[col];
    colK[ni] = (size_t)col * K + lk;
#pragma unroll
    for (int mi = 0; mi < 4; ++mi) {
      acc[mi][ni][0] = bv; acc[mi][ni][1] = bv; acc[mi][ni][2] = bv; acc[mi][ni][3] = bv;
    }
  }

  for (int kk = 0; kk < K; kk += 32) {
    __syncthreads();
#pragma unroll
    for (int s = 0; s < 2; ++s) {
      int slot = s * 256 + tid;
      int r = slot >> 2, kg = (slot & 3) << 3;
      *(bf8*)&AsH[r * 32 + kg] = *(const bf8*)&Ahi[(m0 + r) * K + kk + kg];
      if constexpr (ALO) *(bf8*)&AsL[r * 32 + kg] = *(const bf8*)&Alo[(m0 + r) * K + kk + kg];
    }
    __syncthreads();

    bf8 bh[4], bl[4];
#pragma unroll
    for (int ni = 0; ni < 4; ++ni) {
      bh[ni] = *(const bf8*)&Whi[colK[ni] + kk];
      bl[ni] = *(const bf8*)&Wlo[colK[ni] + kk];
    }
    bf8 ah[4], al[4];
#pragma unroll
    for (int mi = 0; mi < 4; ++mi) {
      ah[mi] = *(const bf8*)&AsH[(wm * 64 + mi * 16 + lrow) * 32 + lk];
      if constexpr (ALO) al[mi] = *(const bf8*)&AsL[(wm * 64 + mi * 16 + lrow) * 32 + lk];
    }
#pragma unroll
    for (int mi = 0; mi < 4; ++mi)
#pragma unroll
      for (int ni = 0; ni < 4; ++ni) {
        acc[mi][ni] = mfma16(ah[mi], bh[ni], acc[mi][ni]);
        acc[mi][ni] = mfma16(ah[mi], bl[ni], acc[mi][ni]);
        if constexpr (ALO) acc[mi][ni] = mfma16(al[mi], bh[ni], acc[mi][ni]);
      }
  }

  f4* C4 = (f4*)Cout;
#pragma unroll
  for (int mi = 0; mi < 4; ++mi) {
    int gg = wm * 4 + mi;
#pragma unroll
    for (int ni = 0; ni < 4; ++ni) {
      int colb = by * 128 + wn * 64 + ni * 16;
      int q  = colb >> 8;
      int ss = (colb >> 5) & 7;
      int wt = (colb >> 4) & 1;
      C4[(((((size_t)bx * 8 + gg) * 8 + ss) * 2 + wt) * 4 + q) * 64 + l] = acc[mi][ni];
    }
  }
}

// ---------- recurrence body: r14 protocol (8-lane polls + early-xg counted ledger) ----------
template <int CHT>
DEVI void recur_body(char* smem, const float* __restrict__ xg, const u16* __restrict__ W2,
                     u16* h, float* cst, u32* tags,
                     int t0, int role, int sub) {
  u16* wlds = (u16*)smem;            // 64 KB W slice
  u16* sbuf = (u16*)(smem + 65536);  // 1 KB transpose buffer
  const int tid = threadIdx.x, l = tid & 63, w = tid >> 6;
  const int lrow = l & 15, lg = l >> 4;
  const int g = sub & 7, s = sub >> 3;
  const int b_base = g << 4;
  const int w1 = w & 1;

  // stage W slice (all 256 threads)
  for (int u = 0; u < 16; ++u) {
    int f = u * 256 + tid;
    int jl = f >> 9, kt = (f >> 6) & 7, e = f & 63;
    int jtg = ((jl >> 1) << 4) + (s << 1) + (jl & 1);
    *(bf8*)&wlds[f << 3] = *(const bf8*)&W2[((size_t)jtg << 12) + (kt << 9) + (e << 3)];
  }

  const int jmy = (s << 5) + (w1 << 4) + lrow;
  float cc4[4] = {0.f, 0.f, 0.f, 0.f};
  if (tid < 128 && t0 > 0) {
#pragma unroll
    for (int rr = 0; rr < 4; ++rr)
      cc4[rr] = cst[(size_t)(b_base + (lg << 2) + rr) * Hh + jmy];
  }
  __syncthreads();                    // covers W staging

  const f4* xb = (const f4*)xg + ((((size_t)g * 8 + s) * 2 + w1) * 4) * 64 + l;
  f4 xgn[4];
  if (tid < 128) {
#pragma unroll
    for (int q = 0; q < 4; ++q) xgn[q] = ld16f((const float*)(xb + (q << 6)));
  }

  for (int t = 0; t < CHT; ++t) {
    const int T = t0 + t;

    if (tid < 128) {
      // ---- sample tags: lanes l<8 only (embedded wave-level vmcnt(0) drains ledger)
      const u32 tagv = (u32)(T + 1);
      u32* tp = tags + ((((size_t)role * (Tt + 1) + T) * 8 + g) << 3) + (l & 7);
      const u16* hr = h + ((size_t)(role ? (T & 1) : T) * Bb + b_base + lrow) * Hh + (lg << 3);

      int seen = 1;
      if (l < 8) seen = (ld_u32_coh(tp) == tagv) ? 1 : 0;
      bf8 af[8];
#pragma unroll
      for (int kt = 0; kt < 8; ++kt) af[kt] = ld16_coh(hr + (kt << 5));
      if (!__all(seen)) {
        int it = 0;
        do {
          if (l < 8) seen = (ld_u32_coh(tp) == tagv) ? 1 : 0;
        } while (!__all(seen) && ++it < (1 << 20));
#pragma unroll
        for (int kt = 0; kt < 8; ++kt) af[kt] = ld16_coh(hr + (kt << 5));
      }
      __builtin_amdgcn_sched_barrier(0);

      f4 acc[4];
#pragma unroll
      for (int q = 0; q < 4; ++q) acc[q] = xgn[q];

      // EARLY next-xg issue (after xgn consumed): ledger = 8 af + 4 xg = 12 outstanding
      {
        int tn = (t + 1 < CHT) ? t + 1 : t;
#pragma unroll
        for (int q = 0; q < 4; ++q)
          xgn[q] = ld16f((const float*)(xb + (size_t)tn * 32768 + (q << 6)));
      }
      __builtin_amdgcn_sched_barrier(0);

      // kt-major MFMA, counted vmcnt waits (af are the 8 oldest of 12 outstanding)
      bf8 bcur[4], bnxt[4];
#pragma unroll
      for (int q = 0; q < 4; ++q)
        bcur[q] = *(const bf8*)&wlds[((((q << 1) | w1) << 3) << 9) + (l << 3)];
#pragma unroll
      for (int kt = 0; kt < 8; ++kt) {
        if (kt < 7) {
#pragma unroll
          for (int q = 0; q < 4; ++q)
            bnxt[q] = *(const bf8*)&wlds[(((((q << 1) | w1) << 3) | (kt + 1)) << 9) + (l << 3)];
        }
        asm volatile("s_waitcnt vmcnt(%0)" :: "i"(11 - kt) : "memory");
        __builtin_amdgcn_sched_barrier(0);
#pragma unroll
        for (int q = 0; q < 4; ++q) acc[q] = mfma16(af[kt], bcur[q], acc[q]);
#pragma unroll
        for (int q = 0; q < 4; ++q) bcur[q] = bnxt[q];
      }

      u16 hv[4];
#pragma unroll
      for (int rr = 0; rr < 4; ++rr) {
        float gi = sigm(acc[0][rr]);
        float gf = sigm(acc[1][rr]);
        float gg = tanh_f(acc[2][rr]);
        float go = sigm(acc[3][rr]);
        float c2 = gf * cc4[rr] + gi * gg;
        cc4[rr] = c2;
        hv[rr] = f2bf(go * tanh_f(c2));
      }
#pragma unroll
      for (int rr = 0; rr < 4; ++rr)
        sbuf[(((lg << 2) + rr) << 5) + (w1 << 4) + lrow] = hv[rr];
    }
    asm volatile("s_waitcnt lgkmcnt(0)\ns_barrier" ::: "memory");
    if (tid < 64) {
      int b = tid >> 2, gg = tid & 3;
      bf8 v = *(const bf8*)&sbuf[(b << 5) + (gg << 3)];
      u16* hw = h + ((size_t)(role ? ((T + 1) & 1) : (T + 1)) * Bb + b_base + b) * Hh
                + (s << 5) + (gg << 3);
      st16_coh(hw, v);
      asm volatile("s_waitcnt vmcnt(0)" ::: "memory");   // stores (+ finished xg) acked
      if (tid == 0) {
        u32* tq = tags + ((((size_t)role * (Tt + 1) + T + 1) * 8 + g) << 3) + s;
        st_u32_coh(tq, (u32)(T + 2));
      }
    }
  }

  if (tid < 128) {
#pragma unroll
    for (int rr = 0; rr < 4; ++rr)
      cst[(size_t)(b_base + (lg << 2) + rr) * Hh + jmy] = cc4[rr];
  }
}

// ---------- fused pipeline dispatch: gemmA(d) || recurL1(d-1) || gemmB(d-2) || recurL2(d-3) ----------
template <int CHT>
__global__ void __launch_bounds__(256) k_mega(
    const u16* gAh, const u16* gAl,
    const u16* W0h, const u16* W0l, const float* b0,
    const u16* gBa,
    const u16* W1h, const u16* W1l, const float* b1,
    float* xgAw, const float* xgAr,
    float* xgBw, const float* xgBr,
    const u16* W2a, const u16* W2b,
    u16* h1, u16* h2r, float* cstA, float* cstB,
    u32* tags, int d) {
  constexpr int NCHT = Tt / CHT;
  constexpr int GA = CHT * 8;        // blocks per GEMM
  __shared__ __align__(16) char smem[66560];
  const int bid = blockIdx.x;
  if (bid < 128) {
    const int role = bid >> 6;
    if (role == 0) {
      if (d < 1 || d > NCHT) return;
      recur_body<CHT>(smem, xgAr, W2a, h1, cstA, tags, (d - 1) * CHT, 0, bid & 63);
    } else {
      if (d < 3 || d > NCHT + 2) return;
      recur_body<CHT>(smem, xgBr, W2b, h2r, cstB, tags, (d - 3) * CHT, 1, bid & 63);
    }
  } else if (bid < 128 + GA) {
    if (d > NCHT - 1) return;
    int q = bid - 128;
    gemm_body<Dd, true>(smem, gAh, gAl, W0h, W0l, b0, xgAw, q & (CHT - 1), q / CHT);
  } else {
    if (d < 2 || d > NCHT + 1) return;
    int q = bid - 128 - GA;
    gemm_body<Hh, false>(smem, gBa, nullptr, W1h, W1l, b1, xgBw, q & (CHT - 1), q / CHT);
  }
}

// ---------- final FC: layer-2 final row = global step 512 -> ring index 0 ----------
__global__ void k_fc(const u16* __restrict__ h2l, const float* __restrict__ Wfc,
                     const float* __restrict__ bfc, float* __restrict__ out) {
  int b = threadIdx.x;
  if (b < Bb) {
    float s = bfc[0];
    for (int j = 0; j < Hh; ++j) s += bf2f(h2l[(size_t)b * Hh + j]) * Wfc[j];
    out[b] = s;
  }
}

// ---------- pipeline driver (templated on chunk size) ----------
template <int CHT>
static void run_pipeline(const u16* Xhi, const u16* Xlo,
                         const u16* W0h, const u16* W0l, const float* b0,
                         const u16* W1h, const u16* W1l, const float* b1,
                         const u16* W2a, const u16* W2b,
                         float* xgA, float* xgB,
                         u16* h1Z, u16* h2r, float* cstA, float* cstB,
                         u32* tags, hipStream_t stream) {
  constexpr int NCHT = Tt / CHT;
  constexpr int MCHT = CHT * Bb;
  constexpr size_t CHFT = (size_t)MCHT * G4;
  for (int dd = 0; dd <= NCHT + 2; ++dd) {
    int ca = dd < NCHT ? dd : NCHT - 1;                         // gemmA chunk (clamped)
    int cb = dd < 2 ? 0 : (dd - 2 < NCHT ? dd - 2 : NCHT - 1);  // gemmB chunk (clamped)
    k_mega<CHT><<<128 + 16 * CHT, 256, 0, stream>>>(
        Xhi + (size_t)ca * MCHT * Dd, Xlo + (size_t)ca * MCHT * Dd,
        W0h, W0l, b0,
        h1Z + (size_t)(cb * CHT + 1) * Bb * Hh,
        W1h, W1l, b1,
        xgA + (size_t)(dd & 1) * CHFT, xgA + (size_t)((dd + 1) & 1) * CHFT,
        xgB + (size_t)(dd & 1) * CHFT, xgB + (size_t)((dd + 1) & 1) * CHFT,
        W2a, W2b, h1Z, h2r, cstA, cstB, tags, dd);
  }
}

// ---------- driver ----------
extern "C" void kernel_launch(void* const* d_in, const int* in_sizes, int n_in,
                              void* d_out, int out_size, void* d_ws, size_t ws_size,
                              hipStream_t stream) {
  const float* X    = (const float*)d_in[0];
  const float* Wih0 = (const float*)d_in[1];
  const float* Whh0 = (const float*)d_in[2];
  const float* bih0 = (const float*)d_in[3];
  const float* bhh0 = (const float*)d_in[4];
  const float* Wih1 = (const float*)d_in[5];
  const float* Whh1 = (const float*)d_in[6];
  const float* bih1 = (const float*)d_in[7];
  const float* bhh1 = (const float*)d_in[8];
  const float* Wfc  = (const float*)d_in[9];
  const float* bfc  = (const float*)d_in[10];

  char* base = (char*)d_ws;
  size_t off = 0;
  auto alloc = [&](size_t bytes) -> char* {
    char* p = base + off;
    off = (off + bytes + 255) & ~(size_t)255;
    return p;
  };

  u16* Xhi = (u16*)alloc((size_t)Bb * Tt * Dd * 2);
  u16* Xlo = (u16*)alloc((size_t)Bb * Tt * Dd * 2);
  u16* W0h = (u16*)alloc((size_t)G4 * Dd * 2);
  u16* W0l = (u16*)alloc((size_t)G4 * Dd * 2);
  u16* W1h = (u16*)alloc((size_t)G4 * Hh * 2);
  u16* W1l = (u16*)alloc((size_t)G4 * Hh * 2);
  u16* W2a = (u16*)alloc((size_t)G4 * Hh * 2);
  u16* W2b = (u16*)alloc((size_t)G4 * Hh * 2);
  float* b0 = (float*)alloc(G4 * 4);
  float* b1 = (float*)alloc(G4 * 4);
  u16* h1Z = (u16*)alloc((size_t)(Tt + 1) * Bb * Hh * 2);   // full rows (row 0 = zeros)
  u16* h2r = (u16*)alloc((size_t)2 * Bb * Hh * 2);          // layer-2 ring-2 rows
  float* cstA = (float*)alloc((size_t)Bb * Hh * 4);
  float* cstB = (float*)alloc((size_t)Bb * Hh * 4);
  u32* tags = (u32*)alloc((size_t)2 * (Tt + 1) * 64 * 4);

  // choose chunk size: CH=64 needs 4 x 33.55 MB xg rings; fall back to CH=32 otherwise
  constexpr size_t CHF32 = (size_t)32 * Bb * G4;   //  4.19M floats -> 16.78 MB
  constexpr size_t CHF64 = (size_t)64 * Bb * G4;   //  8.39M floats -> 33.55 MB
  size_t need64 = off + 4 * CHF64 * 4 + 4096;
  bool use64 = (ws_size >= need64);
  float* xgA;
  float* xgB;
  if (use64) {
    xgA = (float*)alloc(2 * CHF64 * 4);
    xgB = (float*)alloc(2 * CHF64 * 4);
  } else {
    xgA = (float*)alloc(2 * CHF32 * 4);
    xgB = (float*)alloc(2 * CHF32 * 4);
  }

  k_init<<<(2 * (Tt + 1) * 64 + 255) / 256, 256, 0, stream>>>(tags);
  k_zrow<<<(Bb * Hh + 255) / 256, 256, 0, stream>>>(h1Z, h2r);
  k_prep_x<<<(Bb * Tt * Dd) / 256, 256, 0, stream>>>(X, Xhi, Xlo);
  k_split<<<(G4 * Dd) / 256, 256, 0, stream>>>(Wih0, W0h, W0l);
  k_split<<<(G4 * Hh) / 256, 256, 0, stream>>>(Wih1, W1h, W1l);
  k_prep_whh<<<(G4 * Hh) / 256, 256, 0, stream>>>(Whh0, W2a);
  k_prep_whh<<<(G4 * Hh) / 256, 256, 0, stream>>>(Whh1, W2b);
  k_bias<<<4, 256, 0, stream>>>(bih0, bhh0, b0);
  k_bias<<<4, 256, 0, stream>>>(bih1, bhh1, b1);

  if (use64)
    run_pipeline<64>(Xhi, Xlo, W0h, W0l, b0, W1h, W1l, b1, W2a, W2b,
                     xgA, xgB, h1Z, h2r, cstA, cstB, tags, stream);
  else
    run_pipeline<32>(Xhi, Xlo, W0h, W0l, b0, W1h, W1l, b1, W2a, W2b,
                     xgA, xgB, h1Z, h2r, cstA, cstB, tags, stream);

  k_fc<<<1, 128, 0, stream>>>(h2r, Wfc, bfc, (float*)d_out);

  (void)in_sizes; (void)n_in; (void)out_size; (void)ws_size;
}

// Round 16
// 1463.983 us; speedup vs baseline: 1.0622x; 1.0622x over previous
//
#include <hip/hip_runtime.h>

typedef unsigned short u16;
typedef unsigned int u32;
typedef __attribute__((ext_vector_type(8))) short bf8;   // 8 x bf16 MFMA operand
typedef __attribute__((ext_vector_type(4))) float f4;    // MFMA accumulator

#define DEVI static __device__ __forceinline__

constexpr int Bb = 128, Tt = 512, Dd = 128, Hh = 256, G4 = 1024;
constexpr int CH  = 32;            // timesteps per chunk
constexpr int NCH = Tt / CH;       // 16 chunks
constexpr int MCH = CH * Bb;       // 4096 GEMM rows per chunk
constexpr size_t CHF = (size_t)MCH * G4;   // floats per xg chunk

DEVI u16 f2bf(float f) {
  union { float f; u32 u; } v; v.f = f;
  u32 r = v.u + 0x7FFFu + ((v.u >> 16) & 1u);  // RNE
  return (u16)(r >> 16);
}
DEVI float bf2f(u16 b) { union { u32 u; float f; } v; v.u = ((u32)b) << 16; return v.f; }
DEVI float frcp(float x) { return __builtin_amdgcn_rcpf(x); }
DEVI float sigm(float x) { return frcp(1.f + __expf(-x)); }
DEVI float tanh_f(float x) { return 1.f - 2.f * frcp(1.f + __expf(2.f * x)); }
DEVI f4 mfma16(bf8 a, bf8 b, f4 c) {
  return __builtin_amdgcn_mfma_f32_16x16x32_bf16(a, b, c, 0, 0, 0);
}

// ---- device-coherent (MALL-direct, L1/L2-bypass) ops — r8/r10-proven exchange path ----
DEVI u32 ld_u32_coh(const u32* p) {
  u32 r;
  asm volatile("global_load_dword %0, %1, off sc0 sc1\ns_waitcnt vmcnt(0)"
               : "=&v"(r) : "v"(p) : "memory");
  return r;
}
DEVI bf8 ld16_coh(const u16* p) {   // no embedded wait: counted externally
  bf8 r;
  asm volatile("global_load_dwordx4 %0, %1, off sc0 sc1" : "=&v"(r) : "v"(p) : "memory");
  return r;
}
DEVI void st16_coh(u16* p, bf8 v) {
  asm volatile("global_store_dwordx4 %0, %1, off sc0 sc1" :: "v"(p), "v"(v) : "memory");
}
DEVI void st_u32_coh(u32* p, u32 v) {
  asm volatile("global_store_dword %0, %1, off sc0 sc1" :: "v"(p), "v"(v) : "memory");
}
DEVI f4 ld16f(const float* p) {   // plain cached load, asm so compiler adds no waits
  f4 r;
  asm volatile("global_load_dwordx4 %0, %1, off" : "=&v"(r) : "v"(p) : "memory");
  return r;
}

// ---------- prep kernels ----------

__global__ void k_prep_x(const float* __restrict__ X, u16* __restrict__ Xhi, u16* __restrict__ Xlo) {
  size_t idx = (size_t)blockIdx.x * 256 + threadIdx.x;      // (b*T+t)*D + d
  int d = (int)(idx % Dd);
  size_t bt = idx / Dd;
  int b = (int)(bt / Tt), t = (int)(bt % Tt);
  float x = X[idx];
  u16 hi = f2bf(x);
  u16 lo = f2bf(x - bf2f(hi));
  size_t o = ((size_t)t * Bb + b) * Dd + d;
  Xhi[o] = hi; Xlo[o] = lo;
}

__global__ void k_split(const float* __restrict__ W, u16* __restrict__ hi_, u16* __restrict__ lo_) {
  size_t idx = (size_t)blockIdx.x * 256 + threadIdx.x;
  float v = W[idx];
  u16 hi = f2bf(v);
  hi_[idx] = hi;
  lo_[idx] = f2bf(v - bf2f(hi));
}

// Whh[4H,H] -> fragment-linear bf16 W2: offset jtg*4096 + kt*512 + lane*8 + i
__global__ void k_prep_whh(const float* __restrict__ Whh, u16* __restrict__ W2) {
  int idx = blockIdx.x * 256 + threadIdx.x;           // 262144
  int i = idx & 7, lane = (idx >> 3) & 63, kt = (idx >> 9) & 7, jtg = idx >> 12;
  int jp = (jtg << 4) + (lane & 15);
  int k  = ((lane >> 4) << 3) + i + (kt << 5);
  W2[idx] = f2bf(Whh[(size_t)jp * Hh + k]);
}

__global__ void k_bias(const float* __restrict__ a, const float* __restrict__ b, float* __restrict__ o) {
  int i = blockIdx.x * 256 + threadIdx.x;
  if (i < G4) o[i] = a[i] + b[i];
}

// tags[2][Tt+1][8][8]: row 0 = 1 (pre-published), rest 0.
__global__ void k_init(u32* __restrict__ tags) {
  int i = blockIdx.x * 256 + threadIdx.x;
  if (i < 2 * (Tt + 1) * 64) {
    int row = (i >> 6) % (Tt + 1);
    tags[i] = (row == 0) ? 1u : 0u;
  }
}

__global__ void k_zrow(u16* __restrict__ a, u16* __restrict__ b) {
  int i = blockIdx.x * 256 + threadIdx.x;
  if (i < Bb * Hh) { a[i] = 0; b[i] = 0; }
}

// ---------- GEMM body (256 thr): gates = A[M,K] @ W[1024,K]^T + bias -> XGF layout ----------
template <int K, bool ALO>
DEVI void gemm_body(char* smem, const u16* __restrict__ Ahi, const u16* __restrict__ Alo,
                    const u16* __restrict__ Whi, const u16* __restrict__ Wlo,
                    const float* __restrict__ bias, float* __restrict__ Cout,
                    int bx, int by) {
  u16* AsH = (u16*)smem;             // [128][32]
  u16* AsL = (u16*)(smem + 8192);
  const int tid = threadIdx.x, l = tid & 63;
  const int w = tid >> 6, wm = w >> 1, wn = w & 1;
  const int lrow = l & 15, lk = (l >> 4) << 3;
  const size_t m0 = (size_t)bx * 128;
  const int n0 = by * 128;

  f4 acc[4][4];
  size_t colK[4];
#pragma unroll
  for (int ni = 0; ni < 4; ++ni) {
    int col = n0 + wn * 64 + ni * 16 + lrow;
    float bv = bias[col];
    colK[ni] = (size_t)col * K + lk;
#pragma unroll
    for (int mi = 0; mi < 4; ++mi) {
      acc[mi][ni][0] = bv; acc[mi][ni][1] = bv; acc[mi][ni][2] = bv; acc[mi][ni][3] = bv;
    }
  }

  for (int kk = 0; kk < K; kk += 32) {
    __syncthreads();
#pragma unroll
    for (int s = 0; s < 2; ++s) {
      int slot = s * 256 + tid;
      int r = slot >> 2, kg = (slot & 3) << 3;
      *(bf8*)&AsH[r * 32 + kg] = *(const bf8*)&Ahi[(m0 + r) * K + kk + kg];
      if constexpr (ALO) *(bf8*)&AsL[r * 32 + kg] = *(const bf8*)&Alo[(m0 + r) * K + kk + kg];
    }
    __syncthreads();

    bf8 bh[4], bl[4];
#pragma unroll
    for (int ni = 0; ni < 4; ++ni) {
      bh[ni] = *(const bf8*)&Whi[colK[ni] + kk];
      bl[ni] = *(const bf8*)&Wlo[colK[ni] + kk];
    }
    bf8 ah[4], al[4];
#pragma unroll
    for (int mi = 0; mi < 4; ++mi) {
      ah[mi] = *(const bf8*)&AsH[(wm * 64 + mi * 16 + lrow) * 32 + lk];
      if constexpr (ALO) al[mi] = *(const bf8*)&AsL[(wm * 64 + mi * 16 + lrow) * 32 + lk];
    }
#pragma unroll
    for (int mi = 0; mi < 4; ++mi)
#pragma unroll
      for (int ni = 0; ni < 4; ++ni) {
        acc[mi][ni] = mfma16(ah[mi], bh[ni], acc[mi][ni]);
        acc[mi][ni] = mfma16(ah[mi], bl[ni], acc[mi][ni]);
        if constexpr (ALO) acc[mi][ni] = mfma16(al[mi], bh[ni], acc[mi][ni]);
      }
  }

  f4* C4 = (f4*)Cout;
#pragma unroll
  for (int mi = 0; mi < 4; ++mi) {
    int gg = wm * 4 + mi;
#pragma unroll
    for (int ni = 0; ni < 4; ++ni) {
      int colb = by * 128 + wn * 64 + ni * 16;
      int q  = colb >> 8;
      int ss = (colb >> 5) & 7;
      int wt = (colb >> 4) & 1;
      C4[(((((size_t)bx * 8 + gg) * 8 + ss) * 2 + wt) * 4 + q) * 64 + l] = acc[mi][ni];
    }
  }
}

// ---------- recurrence body: r14 protocol (8-lane polls + early-xg counted ledger) ----------
DEVI void recur_body(char* smem, const float* __restrict__ xg, const u16* __restrict__ W2,
                     u16* h, float* cst, u32* tags,
                     int t0, int role, int sub) {
  u16* wlds = (u16*)smem;            // 64 KB W slice
  u16* sbuf = (u16*)(smem + 65536);  // 1 KB transpose buffer
  const int tid = threadIdx.x, l = tid & 63, w = tid >> 6;
  const int lrow = l & 15, lg = l >> 4;
  const int g = sub & 7, s = sub >> 3;
  const int b_base = g << 4;
  const int w1 = w & 1;

  // stage W slice (all 256 threads)
  for (int u = 0; u < 16; ++u) {
    int f = u * 256 + tid;
    int jl = f >> 9, kt = (f >> 6) & 7, e = f & 63;
    int jtg = ((jl >> 1) << 4) + (s << 1) + (jl & 1);
    *(bf8*)&wlds[f << 3] = *(const bf8*)&W2[((size_t)jtg << 12) + (kt << 9) + (e << 3)];
  }

  const int jmy = (s << 5) + (w1 << 4) + lrow;
  float cc4[4] = {0.f, 0.f, 0.f, 0.f};
  if (tid < 128 && t0 > 0) {
#pragma unroll
    for (int rr = 0; rr < 4; ++rr)
      cc4[rr] = cst[(size_t)(b_base + (lg << 2) + rr) * Hh + jmy];
  }
  __syncthreads();                    // covers W staging

  const f4* xb = (const f4*)xg + ((((size_t)g * 8 + s) * 2 + w1) * 4) * 64 + l;
  f4 xgn[4];
  if (tid < 128) {
#pragma unroll
    for (int q = 0; q < 4; ++q) xgn[q] = ld16f((const float*)(xb + (q << 6)));
  }

  for (int t = 0; t < CH; ++t) {
    const int T = t0 + t;

    if (tid < 128) {
      // ---- sample tags: lanes l<8 only (embedded wave-level vmcnt(0) drains ledger)
      const u32 tagv = (u32)(T + 1);
      u32* tp = tags + ((((size_t)role * (Tt + 1) + T) * 8 + g) << 3) + (l & 7);
      const u16* hr = h + ((size_t)(role ? (T & 1) : T) * Bb + b_base + lrow) * Hh + (lg << 3);

      int seen = 1;
      if (l < 8) seen = (ld_u32_coh(tp) == tagv) ? 1 : 0;
      bf8 af[8];
#pragma unroll
      for (int kt = 0; kt < 8; ++kt) af[kt] = ld16_coh(hr + (kt << 5));
      if (!__all(seen)) {
        int it = 0;
        do {
          if (l < 8) seen = (ld_u32_coh(tp) == tagv) ? 1 : 0;
        } while (!__all(seen) && ++it < (1 << 20));
#pragma unroll
        for (int kt = 0; kt < 8; ++kt) af[kt] = ld16_coh(hr + (kt << 5));
      }
      __builtin_amdgcn_sched_barrier(0);

      f4 acc[4];
#pragma unroll
      for (int q = 0; q < 4; ++q) acc[q] = xgn[q];

      // EARLY next-xg issue (after xgn consumed): ledger = 8 af + 4 xg = 12 outstanding
      {
        int tn = (t + 1 < CH) ? t + 1 : t;
#pragma unroll
        for (int q = 0; q < 4; ++q)
          xgn[q] = ld16f((const float*)(xb + (size_t)tn * 32768 + (q << 6)));
      }
      __builtin_amdgcn_sched_barrier(0);

      // kt-major MFMA, counted vmcnt waits (af are the 8 oldest of 12 outstanding)
      bf8 bcur[4], bnxt[4];
#pragma unroll
      for (int q = 0; q < 4; ++q)
        bcur[q] = *(const bf8*)&wlds[((((q << 1) | w1) << 3) << 9) + (l << 3)];
#pragma unroll
      for (int kt = 0; kt < 8; ++kt) {
        if (kt < 7) {
#pragma unroll
          for (int q = 0; q < 4; ++q)
            bnxt[q] = *(const bf8*)&wlds[(((((q << 1) | w1) << 3) | (kt + 1)) << 9) + (l << 3)];
        }
        asm volatile("s_waitcnt vmcnt(%0)" :: "i"(11 - kt) : "memory");
        __builtin_amdgcn_sched_barrier(0);
#pragma unroll
        for (int q = 0; q < 4; ++q) acc[q] = mfma16(af[kt], bcur[q], acc[q]);
#pragma unroll
        for (int q = 0; q < 4; ++q) bcur[q] = bnxt[q];
      }

      u16 hv[4];
#pragma unroll
      for (int rr = 0; rr < 4; ++rr) {
        float gi = sigm(acc[0][rr]);
        float gf = sigm(acc[1][rr]);
        float gg = tanh_f(acc[2][rr]);
        float go = sigm(acc[3][rr]);
        float c2 = gf * cc4[rr] + gi * gg;
        cc4[rr] = c2;
        hv[rr] = f2bf(go * tanh_f(c2));
      }
#pragma unroll
      for (int rr = 0; rr < 4; ++rr)
        sbuf[(((lg << 2) + rr) << 5) + (w1 << 4) + lrow] = hv[rr];
    }
    asm volatile("s_waitcnt lgkmcnt(0)\ns_barrier" ::: "memory");
    if (tid < 64) {
      int b = tid >> 2, gg = tid & 3;
      bf8 v = *(const bf8*)&sbuf[(b << 5) + (gg << 3)];
      u16* hw = h + ((size_t)(role ? ((T + 1) & 1) : (T + 1)) * Bb + b_base + b) * Hh
                + (s << 5) + (gg << 3);
      st16_coh(hw, v);
      asm volatile("s_waitcnt vmcnt(0)" ::: "memory");   // stores (+ finished xg) acked
      if (tid == 0) {
        u32* tq = tags + ((((size_t)role * (Tt + 1) + T + 1) * 8 + g) << 3) + s;
        st_u32_coh(tq, (u32)(T + 2));
      }
    }
  }

  if (tid < 128) {
#pragma unroll
    for (int rr = 0; rr < 4; ++rr)
      cst[(size_t)(b_base + (lg << 2) + rr) * Hh + jmy] = cc4[rr];
  }
}

// ---------- fused pipeline dispatch: gemmA(d) || recurL1(d-1) || gemmB(d-2) || recurL2(d-3) ----------
__global__ void __launch_bounds__(256) k_mega(
    const u16* gAh, const u16* gAl,
    const u16* W0h, const u16* W0l, const float* b0,
    const u16* gBa,
    const u16* W1h, const u16* W1l, const float* b1,
    float* xgAw, const float* xgAr,
    float* xgBw, const float* xgBr,
    const u16* W2a, const u16* W2b,
    u16* h1, u16* h2r, float* cstA, float* cstB,
    u32* tags, int d) {
  __shared__ __align__(16) char smem[66560];
  const int bid = blockIdx.x;
  if (bid < 128) {
    const int role = bid >> 6;
    if (role == 0) {
      if (d < 1 || d > NCH) return;
      recur_body(smem, xgAr, W2a, h1, cstA, tags, (d - 1) * CH, 0, bid & 63);
    } else {
      if (d < 3 || d > NCH + 2) return;
      recur_body(smem, xgBr, W2b, h2r, cstB, tags, (d - 3) * CH, 1, bid & 63);
    }
  } else if (bid < 384) {
    if (d > NCH - 1) return;
    int q = bid - 128;
    gemm_body<Dd, true>(smem, gAh, gAl, W0h, W0l, b0, xgAw, q & 31, q >> 5);
  } else {
    if (d < 2 || d > NCH + 1) return;
    int q = bid - 384;
    gemm_body<Hh, false>(smem, gBa, nullptr, W1h, W1l, b1, xgBw, q & 31, q >> 5);
  }
}

// ---------- final FC: layer-2 final row = global step 512 -> ring index 0 ----------
__global__ void k_fc(const u16* __restrict__ h2l, const float* __restrict__ Wfc,
                     const float* __restrict__ bfc, float* __restrict__ out) {
  int b = threadIdx.x;
  if (b < Bb) {
    float s = bfc[0];
    for (int j = 0; j < Hh; ++j) s += bf2f(h2l[(size_t)b * Hh + j]) * Wfc[j];
    out[b] = s;
  }
}

// ---------- driver ----------
extern "C" void kernel_launch(void* const* d_in, const int* in_sizes, int n_in,
                              void* d_out, int out_size, void* d_ws, size_t ws_size,
                              hipStream_t stream) {
  const float* X    = (const float*)d_in[0];
  const float* Wih0 = (const float*)d_in[1];
  const float* Whh0 = (const float*)d_in[2];
  const float* bih0 = (const float*)d_in[3];
  const float* bhh0 = (const float*)d_in[4];
  const float* Wih1 = (const float*)d_in[5];
  const float* Whh1 = (const float*)d_in[6];
  const float* bih1 = (const float*)d_in[7];
  const float* bhh1 = (const float*)d_in[8];
  const float* Wfc  = (const float*)d_in[9];
  const float* bfc  = (const float*)d_in[10];

  char* base = (char*)d_ws;
  size_t off = 0;
  auto alloc = [&](size_t bytes) -> char* {
    char* p = base + off;
    off = (off + bytes + 255) & ~(size_t)255;
    return p;
  };

  u16* Xhi = (u16*)alloc((size_t)Bb * Tt * Dd * 2);
  u16* Xlo = (u16*)alloc((size_t)Bb * Tt * Dd * 2);
  u16* W0h = (u16*)alloc((size_t)G4 * Dd * 2);
  u16* W0l = (u16*)alloc((size_t)G4 * Dd * 2);
  u16* W1h = (u16*)alloc((size_t)G4 * Hh * 2);
  u16* W1l = (u16*)alloc((size_t)G4 * Hh * 2);
  u16* W2a = (u16*)alloc((size_t)G4 * Hh * 2);
  u16* W2b = (u16*)alloc((size_t)G4 * Hh * 2);
  float* b0 = (float*)alloc(G4 * 4);
  float* b1 = (float*)alloc(G4 * 4);
  float* xgA = (float*)alloc((size_t)2 * CHF * 4);          // ring-2 layer-1 chunks
  float* xgB = (float*)alloc((size_t)2 * CHF * 4);          // ring-2 layer-2 chunks
  u16* h1Z = (u16*)alloc((size_t)(Tt + 1) * Bb * Hh * 2);   // full rows (row 0 = zeros)
  u16* h2r = (u16*)alloc((size_t)2 * Bb * Hh * 2);          // layer-2 ring-2 rows
  float* cstA = (float*)alloc((size_t)Bb * Hh * 4);
  float* cstB = (float*)alloc((size_t)Bb * Hh * 4);
  u32* tags = (u32*)alloc((size_t)2 * (Tt + 1) * 64 * 4);

  k_init<<<(2 * (Tt + 1) * 64 + 255) / 256, 256, 0, stream>>>(tags);
  k_zrow<<<(Bb * Hh + 255) / 256, 256, 0, stream>>>(h1Z, h2r);
  k_prep_x<<<(Bb * Tt * Dd) / 256, 256, 0, stream>>>(X, Xhi, Xlo);
  k_split<<<(G4 * Dd) / 256, 256, 0, stream>>>(Wih0, W0h, W0l);
  k_split<<<(G4 * Hh) / 256, 256, 0, stream>>>(Wih1, W1h, W1l);
  k_prep_whh<<<(G4 * Hh) / 256, 256, 0, stream>>>(Whh0, W2a);
  k_prep_whh<<<(G4 * Hh) / 256, 256, 0, stream>>>(Whh1, W2b);
  k_bias<<<4, 256, 0, stream>>>(bih0, bhh0, b0);
  k_bias<<<4, 256, 0, stream>>>(bih1, bhh1, b1);

  for (int dd = 0; dd <= NCH + 2; ++dd) {
    int ca = dd < NCH ? dd : NCH - 1;                        // gemmA chunk (clamped)
    int cb = dd < 2 ? 0 : (dd - 2 < NCH ? dd - 2 : NCH - 1); // gemmB chunk (clamped)
    k_mega<<<640, 256, 0, stream>>>(
        Xhi + (size_t)ca * MCH * Dd, Xlo + (size_t)ca * MCH * Dd,
        W0h, W0l, b0,
        h1Z + (size_t)(cb * CH + 1) * Bb * Hh,
        W1h, W1l, b1,
        xgA + (size_t)(dd & 1) * CHF, xgA + (size_t)((dd + 1) & 1) * CHF,
        xgB + (size_t)(dd & 1) * CHF, xgB + (size_t)((dd + 1) & 1) * CHF,
        W2a, W2b, h1Z, h2r, cstA, cstB, tags, dd);
  }
  k_fc<<<1, 128, 0, stream>>>(h2r, Wfc, bfc, (float*)d_out);

  (void)in_sizes; (void)n_in; (void)out_size; (void)ws_size;
}